// Round 4
// baseline (1056.763 us; speedup 1.0000x reference)
//
#include <hip/hip_runtime.h>
#include <cstdint>
#include <cstddef>

#define RANK 10

typedef float f2_t __attribute__((ext_vector_type(2)));
typedef float f4_t __attribute__((ext_vector_type(4)));

// Barrier-free streaming design (round 4).
// Insight: x has ZERO cross-lane reuse in this decomposition -- each x element
// feeds exactly one lane's accumulator. So x never touches LDS: each lane
// streams its own 64B/chunk (4 x f4) straight into registers, ping-pong
// double-buffered, with NO barriers in the main loop. Factors (the only
// reused data) are read per-lane from global: the address is uniform per
// half-wave, so L1 serves each instruction as 2 unique 16B sectors broadcast
// to 64 lanes -- same instruction count as the previous ds_read_b128s.
// Rounds 0/3 both plateaued at ~3.7 TB/s delivered with phase-barrier
// structures despite ample bytes in flight; this kernel is the decisive test
// of "lockstep phases throttle delivery" vs "real BW ceiling".
// LDS: only boundary reductions + y (2240 floats used), but DECLARED 32 KB to
// pin LDS-implied occupancy at 5 blocks/CU so the allocator budgets ~102
// VGPRs (rounds 1-2: it spills to reach the LDS-implied block count).
// 5 blocks x 4 waves = 20 waves/CU, every wave independent between matrix
// boundaries (9 __syncthreads total, none in the hot loop).
__global__ __launch_bounds__(256, 4)
void cp_fusion_kernel(const float* __restrict__ x1, const float* __restrict__ x2,
                      const float* __restrict__ x3, const float* __restrict__ f1,
                      const float* __restrict__ f2, const float* __restrict__ f3,
                      const float* __restrict__ fo, float* __restrict__ out)
{
    __shared__ float lds[8192];            // 32 KB declared; [0,2240) used:
                                           // partials [0,1280), y1 @1280,
                                           // y2 @1600, y @1920
    const int tid  = threadIdx.x;
    const int lane = tid & 63;
    const int wid  = __builtin_amdgcn_readfirstlane(tid >> 6);
    const int row_base = blockIdx.x << 5;  // 2048 blocks * 32 rows

    const float* xs[3] = {x1, x2, x3};
    const float* fs[3] = {f1, f2, f3};
    const int    S [3] = {1024, 512, 768};
    const int    NC[3] = {8, 4, 6};

    const int rrow = lane & 31;                      // row this lane computes
    const int cb   = wid * 32 + ((lane >> 5) << 4);  // col base (floats) in chunk

    float acc[RANK];
    f4_t A0, A1, A2, A3, B0, B1, B2, B3;   // x chunk ping-pong (all static idx)

    // 4 x f4 = one 16-col slice of one chunk for this lane
    auto load4 = [&](const float* __restrict__ p, f4_t& v0, f4_t& v1, f4_t& v2, f4_t& v3) {
        v0 = *(const f4_t*)(p + 0);
        v1 = *(const f4_t*)(p + 4);
        v2 = *(const f4_t*)(p + 8);
        v3 = *(const f4_t*)(p + 12);
    };

    // 8 k-pairs x 20 FMAs; factors from global (L1 broadcast, aligned f4s:
    // fp byte offset = 40*(c*128+cb) with cb even -> 16B aligned; kp*80B steps)
    auto chunkFMA = [&](const float* __restrict__ fp,
                       const f4_t& X0, const f4_t& X1, const f4_t& X2, const f4_t& X3) {
        #pragma unroll
        for (int kp = 0; kp < 8; ++kp) {
            const f4_t b0 = *(const f4_t*)(fp + kp * 20 +  0);
            const f4_t b1 = *(const f4_t*)(fp + kp * 20 +  4);
            const f4_t b2 = *(const f4_t*)(fp + kp * 20 +  8);
            const f4_t b3 = *(const f4_t*)(fp + kp * 20 + 12);
            const f4_t b4 = *(const f4_t*)(fp + kp * 20 + 16);
            const f4_t& xq = (kp < 2) ? X0 : (kp < 4) ? X1 : (kp < 6) ? X2 : X3;
            const float xx = xq[(kp & 1) * 2];
            const float xy = xq[(kp & 1) * 2 + 1];
            // k0 = cb+2kp: ranks 0..9 = {b0.xyzw, b1.xyzw, b2.xy}
            acc[0] = fmaf(xx, b0.x, acc[0]);
            acc[1] = fmaf(xx, b0.y, acc[1]);
            acc[2] = fmaf(xx, b0.z, acc[2]);
            acc[3] = fmaf(xx, b0.w, acc[3]);
            acc[4] = fmaf(xx, b1.x, acc[4]);
            acc[5] = fmaf(xx, b1.y, acc[5]);
            acc[6] = fmaf(xx, b1.z, acc[6]);
            acc[7] = fmaf(xx, b1.w, acc[7]);
            acc[8] = fmaf(xx, b2.x, acc[8]);
            acc[9] = fmaf(xx, b2.y, acc[9]);
            // k1 = cb+2kp+1: ranks 0..9 = {b2.zw, b3.xyzw, b4.xyzw}
            acc[0] = fmaf(xy, b2.z, acc[0]);
            acc[1] = fmaf(xy, b2.w, acc[1]);
            acc[2] = fmaf(xy, b3.x, acc[2]);
            acc[3] = fmaf(xy, b3.y, acc[3]);
            acc[4] = fmaf(xy, b3.z, acc[4]);
            acc[5] = fmaf(xy, b3.w, acc[5]);
            acc[6] = fmaf(xy, b4.x, acc[6]);
            acc[7] = fmaf(xy, b4.y, acc[7]);
            acc[8] = fmaf(xy, b4.z, acc[8]);
            acc[9] = fmaf(xy, b4.w, acc[9]);
        }
    };

    // prologue: chunk 0 of matrix 0 -> A regs
    load4(x1 + (size_t)(row_base + rrow) * 1024 + cb, A0, A1, A2, A3);

    #pragma unroll
    for (int a = 0; a < 3; ++a) {
        const float* __restrict__ fa = fs[a];
        const int nc = NC[a];
        const float* __restrict__ xrow = xs[a] + (size_t)(row_base + rrow) * S[a] + cb;

        #pragma unroll
        for (int r = 0; r < RANK; ++r) acc[r] = 0.f;

        // nc is even (8/4/6): 2-chunk ping-pong, A computes even c, B odd.
        #pragma unroll 1
        for (int c = 0; c < nc; c += 2) {
            load4(xrow + (c + 1) * 128, B0, B1, B2, B3);       // c+1 in flight
            chunkFMA(fa + (size_t)(c * 128 + cb) * RANK, A0, A1, A2, A3);
            if (c + 2 < nc) {                                  // c+2 in flight
                load4(xrow + (c + 2) * 128, A0, A1, A2, A3);
            } else if (a < 2) {                                // next matrix chunk 0
                load4(xs[a + 1] + (size_t)(row_base + rrow) * S[a + 1] + cb,
                      A0, A1, A2, A3);
            }
            chunkFMA(fa + (size_t)((c + 1) * 128 + cb) * RANK, B0, B1, B2, B3);
        }

        // ---- a-boundary: fold k-halves, cross-wave reduce through LDS.
        //      (next matrix's chunk-0 loads already issued into A regs; they
        //      keep flying through these barriers.)
        #pragma unroll
        for (int r = 0; r < RANK; ++r)
            acc[r] += __shfl_xor(acc[r], 32);

        __syncthreads();                   // prev boundary's readers done
        if (lane < 32) {
            #pragma unroll
            for (int r = 0; r < RANK; ++r)
                lds[wid * 320 + rrow * 10 + r] = acc[r];
        }
        __syncthreads();                   // partials visible
        if (tid < 32) {
            #pragma unroll
            for (int r = 0; r < RANK; ++r) {
                const float s = lds[      tid * 10 + r] + lds[320 + tid * 10 + r]
                              + lds[640 + tid * 10 + r] + lds[960 + tid * 10 + r];
                if (a == 0)      lds[1280 + tid * 10 + r] = s;
                else if (a == 1) lds[1600 + tid * 10 + r] = s;
                else {
                    const float y0 = lds[1280 + tid * 10 + r];
                    const float y1 = lds[1600 + tid * 10 + r];
                    lds[1920 + tid * 10 + r] = y0 * y1 * s;   // y[row][r]
                }
            }
        }
        __syncthreads();                   // y visible / partials free
    }

    // ---- epilogue: out[32][512] = y[32][10] @ fo^T ----
    // fof loaded only now: its 40 regs never coexist with the main loop.
    const int o0 = (tid & 127) << 2;       // 4 output cols per thread
    const f4_t* __restrict__ fo4 = (const f4_t*)(fo + (size_t)o0 * RANK);
    f4_t fof[10];
    #pragma unroll
    for (int p = 0; p < 10; ++p) fof[p] = fo4[p];

    const float* yb = lds + 1920;
    const int half = tid >> 7;             // waves 0,1 -> even rows; 2,3 -> odd
    #pragma unroll 2
    for (int i = 0; i < 16; ++i) {
        const int row = (i << 1) + half;   // wave-uniform -> y reads broadcast
        float yv[RANK];
        #pragma unroll
        for (int r = 0; r < RANK; ++r) yv[r] = yb[row * RANK + r];
        f4_t o = {0.f, 0.f, 0.f, 0.f};
        #pragma unroll
        for (int d = 0; d < 4; ++d) {
            float s = 0.f;
            #pragma unroll
            for (int r = 0; r < RANK; ++r) {
                const int q = d * RANK + r;
                s = fmaf(yv[r], fof[q >> 2][q & 3], s);
            }
            o[d] = s;
        }
        // streamed once -> nontemporal keeps x resident in L3 across dispatches
        __builtin_nontemporal_store(o, (f4_t*)&out[(size_t)(row_base + row) * 512 + o0]);
    }
}

extern "C" void kernel_launch(void* const* d_in, const int* in_sizes, int n_in,
                              void* d_out, int out_size, void* d_ws, size_t ws_size,
                              hipStream_t stream) {
    const float* x1 = (const float*)d_in[0];
    const float* x2 = (const float*)d_in[1];
    const float* x3 = (const float*)d_in[2];
    const float* f1 = (const float*)d_in[3];
    const float* f2 = (const float*)d_in[4];
    const float* f3 = (const float*)d_in[5];
    const float* fo = (const float*)d_in[6];
    float* out = (float*)d_out;
    (void)in_sizes; (void)n_in; (void)out_size; (void)d_ws; (void)ws_size;

    dim3 grid(2048), block(256);
    hipLaunchKernelGGL(cp_fusion_kernel, grid, block, 0, stream,
                       x1, x2, x3, f1, f2, f3, fo, out);
}